// Round 5
// baseline (89.840 us; speedup 1.0000x reference)
//
#include <hip/hip_runtime.h>

// ConvCaps: b=16, A=32, B=32, K=3, P=4, stride=2, h=w=14 -> oh=ow=6
#define AA 32
#define BB 32
#define CC 16
#define KKA 288
#define OHW 6
#define LL 36
#define NBL 576
#define HH 14
#define WWD 14

// ---- workspace layout ----
// ushort region (from byte 0):
#define W1B_OFF   0ull          // bf16 [288][512][16] = 2,359,296
#define W2B_OFF   2359296ull    // bf16 [288][32][16]  =   147,456
#define PU16_OFF  2506752ull    // bf16 [576][288][16] = 2,654,208
#define AR16_OFF  5160960ull    // bf16 [576][288][32] = 5,308,416
// float region starts at byte 20,938,752:
#define FREG_BYTE 20938752ull
#define AU_F      0ull          // f32 [576][288]      = 165,888
#define ARSUMP_F  165888ull     // f32 [18][576][32]   = 331,776
#define ARSUM_F   497664ull     // f32 [576][32]       =  18,432
#define PREP_F    516096ull     // f32 [2][512][576]   = 589,824

typedef __attribute__((ext_vector_type(8))) short bf16x8;
typedef __attribute__((ext_vector_type(4))) float f32x4;

__device__ __forceinline__ unsigned cvtpk(float lo, float hi) {
    unsigned r;
    asm("v_cvt_pk_bf16_f32 %0, %1, %2" : "=v"(r) : "v"(lo), "v"(hi));
    return r;
}
__device__ __forceinline__ float blo(unsigned u) {
    return __builtin_bit_cast(float, u << 16);
}
__device__ __forceinline__ float bhi(unsigned u) {
    return __builtin_bit_cast(float, u & 0xffff0000u);
}

// ---------------------------------------------------------------------------
// Kernel 0: fused weight-cvt (blocks 0..1223) + patch gather (blocks 1224..1735)
// ---------------------------------------------------------------------------
__global__ __launch_bounds__(256) void k_prep(
    const float* __restrict__ W1, const float* __restrict__ W2,
    const float* __restrict__ a, const float* __restrict__ pose,
    unsigned short* __restrict__ W1b, unsigned short* __restrict__ W2b,
    unsigned short* __restrict__ pu16, float* __restrict__ auf)
{
    __shared__ float ps[16][196];
    __shared__ float as_[196];
    const int tid = threadIdx.x;

    if (blockIdx.x < 1224) {
        size_t i = ((size_t)blockIdx.x * 256 + tid) * 8;
        const float* src;
        unsigned short* dst;
        if (i < 2359296ull) { src = W1 + i; dst = W1b + i; }
        else { src = W2 + (i - 2359296ull); dst = W2b + (i - 2359296ull); }
        float4 v0 = *reinterpret_cast<const float4*>(src);
        float4 v1 = *reinterpret_cast<const float4*>(src + 4);
        uint4 o;
        o.x = cvtpk(v0.x, v0.y);
        o.y = cvtpk(v0.z, v0.w);
        o.z = cvtpk(v1.x, v1.y);
        o.w = cvtpk(v1.z, v1.w);
        *reinterpret_cast<uint4*>(dst) = o;
        return;
    }

    const int bid = blockIdx.x - 1224;
    const int b = bid >> 5, aidx = bid & 31;

    const float* psrc = pose + ((size_t)b * 512 + (size_t)aidx * 16) * 196;
    for (int t = tid; t < 3136; t += 256) ((float*)ps)[t] = psrc[t];
    const float* asrc = a + ((size_t)b * 32 + aidx) * 196;
    if (tid < 196) as_[tid] = asrc[tid];
    __syncthreads();

    for (int t = tid; t < 2592; t += 256) {
        int c2 = t & 7;
        int kk = (t >> 3) % 9;
        int l  = t / 72;
        int oy = l / 6, ox = l - (l / 6) * 6;
        int ki = kk / 3, kj = kk - (kk / 3) * 3;
        int pix = (oy * 2 + ki) * 14 + ox * 2 + kj;
        unsigned v = cvtpk(ps[c2 * 2][pix], ps[c2 * 2 + 1][pix]);
        *reinterpret_cast<unsigned*>(
            pu16 + (((size_t)(b * 36 + l)) * KKA + kk * 32 + aidx) * 16 + c2 * 2) = v;
    }
    for (int t = tid; t < 324; t += 256) {
        int kk = t % 9, l = t / 9;
        int oy = l / 6, ox = l - (l / 6) * 6;
        int ki = kk / 3, kj = kk - (kk / 3) * 3;
        auf[((size_t)(b * 36 + l)) * KKA + kk * 32 + aidx] =
            as_[(oy * 2 + ki) * 14 + ox * 2 + kj];
    }
}

// ---------------------------------------------------------------------------
// Kernel 1: logits via zero-padded 16x16x32 MFMA + softmax (no max-sub:
// |logit| <= ~3 analytically, exp-safe; softmax is shift-invariant).
// Grid (36 bl-tiles, 18 n-ranges of 16); 4 waves each own 4 n.
// ---------------------------------------------------------------------------
__global__ __launch_bounds__(256) void k_logit(
    const unsigned short* __restrict__ W2b, const unsigned short* __restrict__ pu16,
    const float* __restrict__ b2, const float* __restrict__ auf,
    unsigned short* __restrict__ ar16, float* __restrict__ arsump)
{
    __shared__ float b2_s[16][32];
    __shared__ float au_s[16][17];
    __shared__ float asum_s[4][16][32];
    const int bl0 = blockIdx.x * 16;
    const int n0b = blockIdx.y * 16;
    const int tid = threadIdx.x;

    #pragma unroll
    for (int k = 0; k < 2; ++k) {
        int t = tid + k * 256;
        b2_s[t >> 5][t & 31] = b2[(size_t)(n0b + (t >> 5)) * 32 + (t & 31)];
    }
    {
        int blr = tid >> 4, nl = tid & 15;
        au_s[blr][nl] = auf[((size_t)(bl0 + blr)) * KKA + n0b + nl];
    }
    __syncthreads();

    const int w = tid >> 6, lane = tid & 63;
    const int g = lane >> 4, d = lane & 15;
    float asum[8] = {0.f, 0.f, 0.f, 0.f, 0.f, 0.f, 0.f, 0.f};

    #pragma unroll
    for (int nn = 0; nn < 4; ++nn) {
        const int nl = w * 4 + nn;
        const int n  = n0b + nl;
        uint4 a0 = {0, 0, 0, 0}, a1 = {0, 0, 0, 0}, bbv = {0, 0, 0, 0};
        if (g < 2) {
            a0 = *reinterpret_cast<const uint4*>(W2b + ((size_t)n * 32 + d) * 16 + g * 8);
            a1 = *reinterpret_cast<const uint4*>(W2b + ((size_t)n * 32 + 16 + d) * 16 + g * 8);
            bbv = *reinterpret_cast<const uint4*>(
                pu16 + (((size_t)(bl0 + d)) * KKA + n) * 16 + g * 8);
        }
        f32x4 zero = {0.f, 0.f, 0.f, 0.f};
        f32x4 c0 = __builtin_amdgcn_mfma_f32_16x16x32_bf16(
            __builtin_bit_cast(bf16x8, a0), __builtin_bit_cast(bf16x8, bbv), zero, 0, 0, 0);
        f32x4 c1 = __builtin_amdgcn_mfma_f32_16x16x32_bf16(
            __builtin_bit_cast(bf16x8, a1), __builtin_bit_cast(bf16x8, bbv), zero, 0, 0, 0);

        float v[8];
        float s = 0.f;
        #pragma unroll
        for (int i = 0; i < 4; ++i) {
            v[i]     = __expf(c0[i] + b2_s[nl][g * 4 + i]);
            v[4 + i] = __expf(c1[i] + b2_s[nl][16 + g * 4 + i]);
            s += v[i] + v[4 + i];
        }
        s += __shfl_xor(s, 16);
        s += __shfl_xor(s, 32);
        const float scale = au_s[d][nl] / s;
        float p[8];
        #pragma unroll
        for (int i = 0; i < 8; ++i) { p[i] = v[i] * scale; asum[i] += p[i]; }

        unsigned short* dst = ar16 + (((size_t)(bl0 + d)) * KKA + n) * 32;
        uint2 u0, u1;
        u0.x = cvtpk(p[0], p[1]); u0.y = cvtpk(p[2], p[3]);
        u1.x = cvtpk(p[4], p[5]); u1.y = cvtpk(p[6], p[7]);
        *reinterpret_cast<uint2*>(dst + g * 4) = u0;
        *reinterpret_cast<uint2*>(dst + 16 + g * 4) = u1;
    }
    #pragma unroll
    for (int i = 0; i < 4; ++i) {
        asum_s[w][d][g * 4 + i]      = asum[i];
        asum_s[w][d][16 + g * 4 + i] = asum[4 + i];
    }
    __syncthreads();
    #pragma unroll
    for (int k = 0; k < 2; ++k) {
        int idx = tid + k * 256;
        int dd = idx >> 5, j = idx & 31;
        float s = asum_s[0][dd][j] + asum_s[1][dd][j] + asum_s[2][dd][j] + asum_s[3][dd][j];
        arsump[(size_t)blockIdx.y * 18432 + ((size_t)(bl0 + dd)) * 32 + j] = s;
    }
}

// ---------------------------------------------------------------------------
// Kernel 2: finish routing — arsum = sum of 18 partials; a_out = arsum/au_tot.
// ---------------------------------------------------------------------------
__global__ __launch_bounds__(256) void k_finish(
    const float* __restrict__ arsump, const float* __restrict__ auf,
    float* __restrict__ arsum, float* __restrict__ out_a)
{
    const int tid = threadIdx.x;
    const int wid = tid >> 6, lane = tid & 63;
    const int bl = blockIdx.x * 4 + wid;
    const int j = lane & 31, h = lane >> 5;

    float s = 0.f;
    #pragma unroll
    for (int k = 0; k < 9; ++k) {
        int r = h * 9 + k;
        s += arsump[(size_t)r * 18432 + (size_t)bl * 32 + j];
    }
    s += __shfl_xor(s, 32);

    float at = 0.f;
    #pragma unroll
    for (int k = 0; k < 5; ++k) {
        int n = k * 64 + lane;
        if (n < KKA) at += auf[(size_t)bl * KKA + n];
    }
    #pragma unroll
    for (int m = 1; m <= 32; m <<= 1) at += __shfl_xor(at, m);

    if (lane < 32) {
        arsum[(size_t)bl * 32 + j] = s;
        int b = bl / 36, l = bl - (bl / 36) * 36;
        out_a[((size_t)b * 32 + j) * 36 + l] = s / at;
    }
}

// ---------------------------------------------------------------------------
// Kernel 3: MFMA pose contraction, f32 scale-accumulate engine.
// 1D grid 1152 = 36 bl-tiles x 16 j-pairs x 2 K-halves, XCD-swizzled so that
// each XCD keeps one z-half of pu + 4 jp W1b slices L2-resident.
// Per n: zero-padded 16x16x32 MFMA (pure W1 x pu) -> 4 f32, then
// acc[i] += cd[i] * ar[bl,n,j]  (f32 FMA, no bf16 repack).
// 4 waves = 2 jl x 2 h(72-n halves); cross-h reduce in LDS.
// ---------------------------------------------------------------------------
__global__ __launch_bounds__(256) void k_pose(
    const unsigned short* __restrict__ W1b, const unsigned short* __restrict__ pu16,
    const unsigned short* __restrict__ ar16, const float* __restrict__ arsum,
    float* __restrict__ prep)
{
    __shared__ unsigned short pu_s[2][2176];   // [h][16 bl x 136] (8n*16c + 8 pad)
    __shared__ unsigned arn_s[16][145];        // [bl][nl], nl in z-range 0..143
    __shared__ float red_s[2][256];

    // XCD swizzle: bid -> (xcd = bid&7), seq; group g = (seq/36)*8 + xcd,
    // tile r = seq%36.  g = jp*2 + z  => z constant per XCD, 4 jp per XCD.
    const int bid = blockIdx.x;
    const int xcd = bid & 7;
    const int seq = bid >> 3;
    const int gq  = seq / 36;
    const int r   = seq - gq * 36;
    const int g_  = gq * 8 + xcd;
    const int jp  = g_ >> 1;
    const int z   = g_ & 1;
    const int bl0 = r * 16;

    const int tid = threadIdx.x;
    const int w = tid >> 6, lane = tid & 63;
    const int jl = w >> 1, h = w & 1;
    const int g = lane >> 4, d = lane & 15;
    const int jg = jp * 2 + jl;

    // stage ar for this (bl-tile, jp, z): uint packs the j-pair
    for (int t = tid; t < 2304; t += 256) {
        int blr = t / 144, nl = t - blr * 144;
        arn_s[blr][nl] = *reinterpret_cast<const unsigned*>(
            ar16 + (((size_t)(bl0 + blr)) * KKA + z * 144 + nl) * 32 + jp * 2);
    }

    f32x4 acc = {0.f, 0.f, 0.f, 0.f};
    const f32x4 zero = {0.f, 0.f, 0.f, 0.f};

    for (int ci = 0; ci < 9; ++ci) {
        __syncthreads();
        // stage pu: 2 h x 16 bl x 8 n x 16 c bf16 (4 uint2 per thread)
        #pragma unroll
        for (int k = 0; k < 4; ++k) {
            int idx = tid + k * 256;
            int hh = idx >> 9, rr = idx & 511;
            int nl8 = rr >> 6, blr = (rr >> 2) & 15, q4 = rr & 3;
            uint2 v = *reinterpret_cast<const uint2*>(
                pu16 + (((size_t)(bl0 + blr)) * KKA
                        + z * 144 + hh * 72 + ci * 8 + nl8) * 16 + q4 * 4);
            *reinterpret_cast<uint2*>(&pu_s[hh][blr * 136 + nl8 * 16 + q4 * 4]) = v;
        }
        __syncthreads();
        #pragma unroll
        for (int nl = 0; nl < 8; ++nl) {
            const int nlg = h * 72 + ci * 8 + nl;   // n within z-range
            const int n   = z * 144 + nlg;
            uint4 a4 = {0, 0, 0, 0}, b4 = {0, 0, 0, 0};
            if (g < 2) {
                a4 = *reinterpret_cast<const uint4*>(
                    W1b + ((size_t)n * 512 + jg * 16 + d) * 16 + g * 8);
                b4 = *reinterpret_cast<const uint4*>(
                    &pu_s[h][d * 136 + nl * 16 + g * 8]);
            }
            f32x4 cd = __builtin_amdgcn_mfma_f32_16x16x32_bf16(
                __builtin_bit_cast(bf16x8, a4), __builtin_bit_cast(bf16x8, b4),
                zero, 0, 0, 0);
            unsigned av = arn_s[d][nlg];
            float s = jl ? bhi(av) : blo(av);
            #pragma unroll
            for (int i = 0; i < 4; ++i)
                acc[i] = fmaf(cd[i], s, acc[i]);
        }
    }

    __syncthreads();
    if (h == 1) {
        #pragma unroll
        for (int i = 0; i < 4; ++i)
            red_s[jl][(g * 4 + i) * 16 + d] = acc[i];
    }
    __syncthreads();
    if (h == 0) {
        const int bl = bl0 + d;
        const float inv = 1.0f / arsum[(size_t)bl * 32 + jg];
        #pragma unroll
        for (int i = 0; i < 4; ++i) {
            float vv = (acc[i] + red_s[jl][(g * 4 + i) * 16 + d]) * inv;
            prep[((size_t)z * 512 + jg * 16 + g * 4 + i) * NBL + bl] = vv;
        }
    }
}

// ---------------------------------------------------------------------------
// Kernel 4: BatchNorm (batch stats, biased var) + layout to [b, 512, 6, 6].
// ---------------------------------------------------------------------------
__global__ __launch_bounds__(256) void k_bn(
    const float* __restrict__ prep, const float* __restrict__ gamma,
    const float* __restrict__ beta, float* __restrict__ out_pose)
{
    const int tid = threadIdx.x;
    const int wid = tid >> 6, lane = tid & 63;
    const int ch  = blockIdx.x * 4 + wid;
    const float* p0 = prep + (size_t)ch * NBL;
    const float* p1 = p0 + 294912;

    float sum = 0.f, sq = 0.f;
    float v[9];
    #pragma unroll
    for (int k = 0; k < 9; ++k) {
        int i = lane + k * 64;
        float x = p0[i] + p1[i];
        v[k] = x;
        sum += x;
        sq  += x * x;
    }
    #pragma unroll
    for (int msk = 32; msk >= 1; msk >>= 1) {
        sum += __shfl_xor(sum, msk);
        sq  += __shfl_xor(sq, msk);
    }
    const float mean = sum * (1.f / 576.f);
    const float var  = sq * (1.f / 576.f) - mean * mean;
    const float inv  = rsqrtf(var + 1e-5f);
    const float sc   = gamma[ch] * inv;
    const float sh   = beta[ch] - mean * sc;
    #pragma unroll
    for (int k = 0; k < 9; ++k) {
        int i = lane + k * 64;
        int b = i / 36;
        int l = i - b * 36;
        out_pose[(size_t)b * 18432 + (size_t)ch * 36 + l] = v[k] * sc + sh;
    }
}

extern "C" void kernel_launch(void* const* d_in, const int* in_sizes, int n_in,
                              void* d_out, int out_size, void* d_ws, size_t ws_size,
                              hipStream_t stream)
{
    const float* a     = (const float*)d_in[0];
    const float* pose  = (const float*)d_in[1];
    const float* W1    = (const float*)d_in[2];
    const float* W2    = (const float*)d_in[3];
    const float* b2    = (const float*)d_in[4];
    const float* gamma = (const float*)d_in[5];
    const float* beta  = (const float*)d_in[6];
    float* out      = (float*)d_out;
    float* out_a    = out;              // [16, 32, 6, 6]
    float* out_pose = out + 18432;      // [16, 512, 6, 6]

    unsigned short* wsu = (unsigned short*)d_ws;
    unsigned short* W1b   = wsu + W1B_OFF;
    unsigned short* W2b   = wsu + W2B_OFF;
    unsigned short* pu16  = wsu + PU16_OFF;
    unsigned short* ar16  = wsu + AR16_OFF;
    float* wsf    = (float*)((char*)d_ws + FREG_BYTE);
    float* auf    = wsf + AU_F;
    float* arsump = wsf + ARSUMP_F;
    float* arsumv = wsf + ARSUM_F;
    float* prep   = wsf + PREP_F;

    hipLaunchKernelGGL(k_prep, dim3(1736), dim3(256), 0, stream,
                       W1, W2, a, pose, W1b, W2b, pu16, auf);
    hipLaunchKernelGGL(k_logit, dim3(36, 18), dim3(256), 0, stream,
                       W2b, pu16, b2, auf, ar16, arsump);
    hipLaunchKernelGGL(k_finish, dim3(144), dim3(256), 0, stream,
                       arsump, auf, arsumv, out_a);
    hipLaunchKernelGGL(k_pose, dim3(1152), dim3(256), 0, stream,
                       W1b, pu16, ar16, arsumv, prep);
    hipLaunchKernelGGL(k_bn, dim3(128), dim3(256), 0, stream,
                       prep, gamma, beta, out_pose);
}

// Round 6
// 38.995 us; speedup vs baseline: 2.3039x; 2.3039x over previous
//
#include <hip/hip_runtime.h>

// ConvCaps: b=16, A=32, B=32, K=3, P=4, stride=2, h=w=14 -> oh=ow=6
#define AA 32
#define BB 32
#define CC 16
#define KKA 288
#define OHW 6
#define LL 36
#define NBL 576
#define HH 14
#define WWD 14

// ---- workspace layout ----
// ushort region (from byte 0):
#define W1B_OFF   0ull          // bf16 [288][512][16]  (n-major, ch, c)
#define W2B_OFF   2359296ull    // bf16 [288][32][16]
#define PU16_OFF  2506752ull    // bf16 [288][576][16]  (n, bl, c)  = 2,654,208
#define AR16_OFF  5160960ull    // bf16 [288][16jp][576bl][2j]      = 5,308,416
// float region starts at byte 20,938,752:
#define FREG_BYTE 20938752ull
#define AU_F      0ull          // f32 [576][288]      = 165,888
#define ARSUMP_F  165888ull     // f32 [18][576][32]   = 331,776
#define INV_F     497664ull     // f32 [32][576]       =  18,432
#define PREP_F    516096ull     // f32 [4][512][576]   = 1,179,648

typedef __attribute__((ext_vector_type(8))) short bf16x8;
typedef __attribute__((ext_vector_type(4))) float f32x4;
typedef __attribute__((ext_vector_type(16))) float f32x16;

__device__ __forceinline__ unsigned cvtpk(float lo, float hi) {
    unsigned r;
    asm("v_cvt_pk_bf16_f32 %0, %1, %2" : "=v"(r) : "v"(lo), "v"(hi));
    return r;
}
__device__ __forceinline__ float blo(unsigned u) {
    return __builtin_bit_cast(float, u << 16);
}
__device__ __forceinline__ float bhi(unsigned u) {
    return __builtin_bit_cast(float, u & 0xffff0000u);
}

// ---------------------------------------------------------------------------
// Kernel 0: fused weight-cvt (blocks 0..1223) + patch gather (blocks 1224..1735)
// pu16 is written in [n][bl][c] order; auf in [bl][n].
// ---------------------------------------------------------------------------
__global__ __launch_bounds__(256) void k_prep(
    const float* __restrict__ W1, const float* __restrict__ W2,
    const float* __restrict__ a, const float* __restrict__ pose,
    unsigned short* __restrict__ W1b, unsigned short* __restrict__ W2b,
    unsigned short* __restrict__ pu16, float* __restrict__ auf)
{
    __shared__ float ps[16][196];
    __shared__ float as_[196];
    const int tid = threadIdx.x;

    if (blockIdx.x < 1224) {
        size_t i = ((size_t)blockIdx.x * 256 + tid) * 8;
        const float* src;
        unsigned short* dst;
        if (i < 2359296ull) { src = W1 + i; dst = W1b + i; }
        else { src = W2 + (i - 2359296ull); dst = W2b + (i - 2359296ull); }
        float4 v0 = *reinterpret_cast<const float4*>(src);
        float4 v1 = *reinterpret_cast<const float4*>(src + 4);
        uint4 o;
        o.x = cvtpk(v0.x, v0.y);
        o.y = cvtpk(v0.z, v0.w);
        o.z = cvtpk(v1.x, v1.y);
        o.w = cvtpk(v1.z, v1.w);
        *reinterpret_cast<uint4*>(dst) = o;
        return;
    }

    const int bid = blockIdx.x - 1224;
    const int b = bid >> 5, aidx = bid & 31;

    const float* psrc = pose + ((size_t)b * 512 + (size_t)aidx * 16) * 196;
    for (int t = tid; t < 3136; t += 256) ((float*)ps)[t] = psrc[t];
    const float* asrc = a + ((size_t)b * 32 + aidx) * 196;
    if (tid < 196) as_[tid] = asrc[tid];
    __syncthreads();

    // pu16[n = kk*32+aidx][bl = b*36+l][c]: 9kk x 36l x 4 c-quads = 1296 uint2
    for (int t = tid; t < 1296; t += 256) {
        int quad = t & 3;
        int l = (t >> 2) % 36;
        int kk = t / 144;
        int oy = l / 6, ox = l - (l / 6) * 6;
        int ki = kk / 3, kj = kk - (kk / 3) * 3;
        int pix = (oy * 2 + ki) * 14 + ox * 2 + kj;
        uint2 v;
        v.x = cvtpk(ps[quad * 4 + 0][pix], ps[quad * 4 + 1][pix]);
        v.y = cvtpk(ps[quad * 4 + 2][pix], ps[quad * 4 + 3][pix]);
        *reinterpret_cast<uint2*>(
            pu16 + (((size_t)(kk * 32 + aidx)) * 576 + b * 36 + l) * 16 + quad * 4) = v;
    }
    for (int t = tid; t < 324; t += 256) {
        int kk = t % 9, l = t / 9;
        int oy = l / 6, ox = l - (l / 6) * 6;
        int ki = kk / 3, kj = kk - (kk / 3) * 3;
        auf[((size_t)(b * 36 + l)) * KKA + kk * 32 + aidx] =
            as_[(oy * 2 + ki) * 14 + ox * 2 + kj];
    }
}

// ---------------------------------------------------------------------------
// Kernel 1: logits via zero-padded 16x16x32 MFMA + softmax (no max-sub:
// |logit| <= ~3 analytically, exp-safe; softmax is shift-invariant).
// Grid (36 bl-tiles, 18 n-ranges of 16); 4 waves each own 4 n.
// Writes ar (bf16, = a_u*softmax) at [n][jp][bl][2] and arsump[18][576][32].
// ---------------------------------------------------------------------------
__global__ __launch_bounds__(256) void k_logit(
    const unsigned short* __restrict__ W2b, const unsigned short* __restrict__ pu16,
    const float* __restrict__ b2, const float* __restrict__ auf,
    unsigned* __restrict__ aru, float* __restrict__ arsump)
{
    __shared__ float b2_s[16][32];
    __shared__ float au_s[16][17];
    __shared__ float asum_s[4][16][32];
    const int bl0 = blockIdx.x * 16;
    const int n0b = blockIdx.y * 16;
    const int tid = threadIdx.x;

    #pragma unroll
    for (int k = 0; k < 2; ++k) {
        int t = tid + k * 256;
        b2_s[t >> 5][t & 31] = b2[(size_t)(n0b + (t >> 5)) * 32 + (t & 31)];
    }
    {
        int blr = tid >> 4, nl = tid & 15;
        au_s[blr][nl] = auf[((size_t)(bl0 + blr)) * KKA + n0b + nl];
    }
    __syncthreads();

    const int w = tid >> 6, lane = tid & 63;
    const int g = lane >> 4, d = lane & 15;
    float asum[8] = {0.f, 0.f, 0.f, 0.f, 0.f, 0.f, 0.f, 0.f};

    #pragma unroll
    for (int nn = 0; nn < 4; ++nn) {
        const int nl = w * 4 + nn;
        const int n  = n0b + nl;
        uint4 a0 = {0, 0, 0, 0}, a1 = {0, 0, 0, 0}, bbv = {0, 0, 0, 0};
        if (g < 2) {
            a0 = *reinterpret_cast<const uint4*>(W2b + ((size_t)n * 32 + d) * 16 + g * 8);
            a1 = *reinterpret_cast<const uint4*>(W2b + ((size_t)n * 32 + 16 + d) * 16 + g * 8);
            bbv = *reinterpret_cast<const uint4*>(
                pu16 + ((size_t)n * 576 + bl0 + d) * 16 + g * 8);
        }
        f32x4 zero = {0.f, 0.f, 0.f, 0.f};
        f32x4 c0 = __builtin_amdgcn_mfma_f32_16x16x32_bf16(
            __builtin_bit_cast(bf16x8, a0), __builtin_bit_cast(bf16x8, bbv), zero, 0, 0, 0);
        f32x4 c1 = __builtin_amdgcn_mfma_f32_16x16x32_bf16(
            __builtin_bit_cast(bf16x8, a1), __builtin_bit_cast(bf16x8, bbv), zero, 0, 0, 0);

        float v[8];
        float s = 0.f;
        #pragma unroll
        for (int i = 0; i < 4; ++i) {
            v[i]     = __expf(c0[i] + b2_s[nl][g * 4 + i]);
            v[4 + i] = __expf(c1[i] + b2_s[nl][16 + g * 4 + i]);
            s += v[i] + v[4 + i];
        }
        s += __shfl_xor(s, 16);
        s += __shfl_xor(s, 32);
        const float scale = au_s[d][nl] / s;
        float p[8];
        #pragma unroll
        for (int i = 0; i < 8; ++i) { p[i] = v[i] * scale; asum[i] += p[i]; }

        // ar[n][jp][bl][2]: lane's j's are {g*4..g*4+3, 16+g*4..16+g*4+3}
        aru[((size_t)n * 16 + g * 2    ) * 576 + bl0 + d] = cvtpk(p[0], p[1]);
        aru[((size_t)n * 16 + g * 2 + 1) * 576 + bl0 + d] = cvtpk(p[2], p[3]);
        aru[((size_t)n * 16 + 8 + g * 2    ) * 576 + bl0 + d] = cvtpk(p[4], p[5]);
        aru[((size_t)n * 16 + 8 + g * 2 + 1) * 576 + bl0 + d] = cvtpk(p[6], p[7]);
    }
    #pragma unroll
    for (int i = 0; i < 4; ++i) {
        asum_s[w][d][g * 4 + i]      = asum[i];
        asum_s[w][d][16 + g * 4 + i] = asum[4 + i];
    }
    __syncthreads();
    #pragma unroll
    for (int k = 0; k < 2; ++k) {
        int idx = tid + k * 256;
        int dd = idx >> 5, j = idx & 31;
        float s = asum_s[0][dd][j] + asum_s[1][dd][j] + asum_s[2][dd][j] + asum_s[3][dd][j];
        arsump[(size_t)blockIdx.y * 18432 + ((size_t)(bl0 + dd)) * 32 + j] = s;
    }
}

// ---------------------------------------------------------------------------
// Kernel 2: finish routing — inv[j][bl] = 1/arsum; a_out = arsum/au_tot.
// ---------------------------------------------------------------------------
__global__ __launch_bounds__(256) void k_finish(
    const float* __restrict__ arsump, const float* __restrict__ auf,
    float* __restrict__ invarsum, float* __restrict__ out_a)
{
    const int tid = threadIdx.x;
    const int wid = tid >> 6, lane = tid & 63;
    const int bl = blockIdx.x * 4 + wid;
    const int j = lane & 31, h = lane >> 5;

    float s = 0.f;
    #pragma unroll
    for (int k = 0; k < 9; ++k) {
        int r = h * 9 + k;
        s += arsump[(size_t)r * 18432 + (size_t)bl * 32 + j];
    }
    s += __shfl_xor(s, 32);

    float at = 0.f;
    #pragma unroll
    for (int k = 0; k < 5; ++k) {
        int n = k * 64 + lane;
        if (n < KKA) at += auf[(size_t)bl * KKA + n];
    }
    #pragma unroll
    for (int m = 1; m <= 32; m <<= 1) at += __shfl_xor(at, m);

    if (lane < 32) {
        invarsum[(size_t)j * 576 + bl] = 1.0f / s;
        int b = bl / 36, l = bl - (bl / 36) * 36;
        out_a[((size_t)b * 32 + j) * 36 + l] = s / at;
    }
}

// ---------------------------------------------------------------------------
// Kernel 3: pose contraction via 32x32x16 MFMA, all-global operands.
// Grid 1152 = 18 bl-tiles(32) x 16 jp x 4 n-quarters(72), XCD-swizzled.
// 4 waves split the n-quarter (18 n each). Per n: one fully-dense MFMA
// (A = W1b[n] 32ch x 16c, B = pu[n] 16c x 32bl), then 16 f32 FMAs scaling
// by ar[n] (regs 0-7 -> j=jp*2, regs 8-15 -> j=jp*2+1). No LDS/barriers in
// the loop; one cross-wave reduce at the end; x inv(arsum) in epilogue.
// ---------------------------------------------------------------------------
__global__ __launch_bounds__(256) void k_pose(
    const unsigned short* __restrict__ W1b, const unsigned short* __restrict__ pu16,
    const unsigned* __restrict__ aru, const float* __restrict__ invarsum,
    float* __restrict__ prep)
{
    __shared__ float red_s[3][16][64];   // 12 KB

    const int bid = blockIdx.x;
    const int wg  = (bid & 7) * 144 + (bid >> 3);   // bijective (1152 % 8 == 0)
    const int q   = wg / 288;                        // n-quarter
    const int rem = wg - q * 288;
    const int jp  = rem / 18;
    const int bl0 = (rem - jp * 18) * 32;

    const int tid = threadIdx.x;
    const int w = tid >> 6, lane = tid & 63;
    const int col = lane & 31, kg = lane >> 5;

    const unsigned short* wp = W1b + ((size_t)(jp * 32 + col)) * 16 + kg * 8;
    const unsigned short* pp = pu16 + ((size_t)(bl0 + col)) * 16 + kg * 8;
    const unsigned* ap = aru + (size_t)jp * 576 + bl0 + col;
    const int n0 = q * 72 + w * 18;

    float acc[16];
    #pragma unroll
    for (int i = 0; i < 16; ++i) acc[i] = 0.f;
    f32x16 zv = {0.f,0.f,0.f,0.f,0.f,0.f,0.f,0.f,0.f,0.f,0.f,0.f,0.f,0.f,0.f,0.f};

    #pragma unroll 6
    for (int i = 0; i < 18; ++i) {
        const size_t n = (size_t)(n0 + i);
        uint4 a4 = *reinterpret_cast<const uint4*>(wp + n * 8192);   // 512*16
        uint4 b4 = *reinterpret_cast<const uint4*>(pp + n * 9216);   // 576*16
        unsigned av = ap[n * 9216];                                  // 16*576
        f32x16 cd = __builtin_amdgcn_mfma_f32_32x32x16_bf16(
            __builtin_bit_cast(bf16x8, a4), __builtin_bit_cast(bf16x8, b4),
            zv, 0, 0, 0);
        float slo = blo(av), shi = bhi(av);
        #pragma unroll
        for (int r = 0; r < 8; ++r)  acc[r] = fmaf(cd[r], slo, acc[r]);
        #pragma unroll
        for (int r = 8; r < 16; ++r) acc[r] = fmaf(cd[r], shi, acc[r]);
    }

    if (w > 0) {
        #pragma unroll
        for (int i = 0; i < 16; ++i) red_s[w - 1][i][lane] = acc[i];
    }
    __syncthreads();
    if (w == 0) {
        const float ilo = invarsum[(size_t)(jp * 2) * 576 + bl0 + col];
        const float ihi = invarsum[(size_t)(jp * 2 + 1) * 576 + bl0 + col];
        #pragma unroll
        for (int i = 0; i < 16; ++i) {
            float v = acc[i] + red_s[0][i][lane] + red_s[1][i][lane] + red_s[2][i][lane];
            int r = (i & 3) + 8 * (i >> 2) + 4 * kg;       // C row (m74/m101 layout)
            float vv = v * (i < 8 ? ilo : ihi);
            prep[((size_t)q * 512 + jp * 32 + r) * NBL + bl0 + col] = vv;
        }
    }
}

// ---------------------------------------------------------------------------
// Kernel 4: BatchNorm (batch stats, biased var) + layout to [b, 512, 6, 6].
// Sums the 4 n-quarter planes of prep.
// ---------------------------------------------------------------------------
__global__ __launch_bounds__(256) void k_bn(
    const float* __restrict__ prep, const float* __restrict__ gamma,
    const float* __restrict__ beta, float* __restrict__ out_pose)
{
    const int tid = threadIdx.x;
    const int wid = tid >> 6, lane = tid & 63;
    const int ch  = blockIdx.x * 4 + wid;
    const float* p0 = prep + (size_t)ch * NBL;

    float sum = 0.f, sq = 0.f;
    float v[9];
    #pragma unroll
    for (int k = 0; k < 9; ++k) {
        int i = lane + k * 64;
        float x = p0[i] + p0[i + 294912] + p0[i + 2 * 294912] + p0[i + 3 * 294912];
        v[k] = x;
        sum += x;
        sq  += x * x;
    }
    #pragma unroll
    for (int msk = 32; msk >= 1; msk >>= 1) {
        sum += __shfl_xor(sum, msk);
        sq  += __shfl_xor(sq, msk);
    }
    const float mean = sum * (1.f / 576.f);
    const float var  = sq * (1.f / 576.f) - mean * mean;
    const float inv  = rsqrtf(var + 1e-5f);
    const float sc   = gamma[ch] * inv;
    const float sh   = beta[ch] - mean * sc;
    #pragma unroll
    for (int k = 0; k < 9; ++k) {
        int i = lane + k * 64;
        int b = i / 36;
        int l = i - b * 36;
        out_pose[(size_t)b * 18432 + (size_t)ch * 36 + l] = v[k] * sc + sh;
    }
}

extern "C" void kernel_launch(void* const* d_in, const int* in_sizes, int n_in,
                              void* d_out, int out_size, void* d_ws, size_t ws_size,
                              hipStream_t stream)
{
    const float* a     = (const float*)d_in[0];
    const float* pose  = (const float*)d_in[1];
    const float* W1    = (const float*)d_in[2];
    const float* W2    = (const float*)d_in[3];
    const float* b2    = (const float*)d_in[4];
    const float* gamma = (const float*)d_in[5];
    const float* beta  = (const float*)d_in[6];
    float* out      = (float*)d_out;
    float* out_a    = out;              // [16, 32, 6, 6]
    float* out_pose = out + 18432;      // [16, 512, 6, 6]

    unsigned short* wsu = (unsigned short*)d_ws;
    unsigned short* W1b   = wsu + W1B_OFF;
    unsigned short* W2b   = wsu + W2B_OFF;
    unsigned short* pu16  = wsu + PU16_OFF;
    unsigned*       aru   = (unsigned*)(wsu + AR16_OFF);
    float* wsf    = (float*)((char*)d_ws + FREG_BYTE);
    float* auf    = wsf + AU_F;
    float* arsump = wsf + ARSUMP_F;
    float* invv   = wsf + INV_F;
    float* prep   = wsf + PREP_F;

    hipLaunchKernelGGL(k_prep, dim3(1736), dim3(256), 0, stream,
                       W1, W2, a, pose, W1b, W2b, pu16, auf);
    hipLaunchKernelGGL(k_logit, dim3(36, 18), dim3(256), 0, stream,
                       W2b, pu16, b2, auf, aru, arsump);
    hipLaunchKernelGGL(k_finish, dim3(144), dim3(256), 0, stream,
                       arsump, auf, invv, out_a);
    hipLaunchKernelGGL(k_pose, dim3(1152), dim3(256), 0, stream,
                       W1b, pu16, aru, invv, prep);
    hipLaunchKernelGGL(k_bn, dim3(128), dim3(256), 0, stream,
                       prep, gamma, beta, out_pose);
}